// Round 8
// baseline (156.985 us; speedup 1.0000x reference)
//
#include <hip/hip_runtime.h>
#include <stdint.h>

#define C_CH   1024
#define T_DIM  16384
#define NSTEPS (T_DIM - 16)   // 16368
#define PAD    8
#define TP     (T_DIM + 16)   // padded time length 16400
#define SEG    256            // time steps per lane

// ws layout:
//   [0, 8*T_DIM*sizeof(double))  : double partial[8][T_DIM]   (1 MiB)
//   [1 MiB, +TP*4)               : float  colmean[TP]
#define WS_CM_OFFSET (8u * T_DIM * sizeof(double))

// ---------------- Kernel 1: per-row-chunk column partial sums ----------------
// (32,8) x 128 thr: each block streams a 2 KB column footprint across 128 rows
// (vs 1 KB x 512 streams before): 2x DRAM granule, half the concurrent streams.
// unroll 16 -> 16 float4 loads (32 KB/block) in flight. f64 accumulate (exact).
__global__ __launch_bounds__(128) void colsum_partial(const float* __restrict__ inp,
                                                      double* __restrict__ part) {
    int col4 = (blockIdx.x * 128 + threadIdx.x) * 4;  // 0..16380 step 4
    int rc   = blockIdx.y;                            // 0..7 (row chunk of 128)
    const float* p = inp + (size_t)rc * 128 * T_DIM + col4;
    double ax = 0.0, ay = 0.0, az = 0.0, aw = 0.0;
    #pragma unroll 16
    for (int r = 0; r < 128; ++r) {
        float4 v = *(const float4*)(p + (size_t)r * T_DIM);
        ax += (double)v.x; ay += (double)v.y; az += (double)v.z; aw += (double)v.w;
    }
    double* q = part + (size_t)rc * T_DIM + col4;
    q[0] = ax; q[1] = ay; q[2] = az; q[3] = aw;
}

// ---------------- Kernel 2: reduce partials -> padded column means, + tail copy ----------------
__global__ void colmean_tail(const double* __restrict__ part, const float* __restrict__ inp,
                             float* __restrict__ cm, float* __restrict__ out) {
    int i = blockIdx.x * 256 + threadIdx.x;   // 0..16639
    if (i < TP) {
        float v = 0.0f;
        if (i >= PAD && i < T_DIM + PAD) {
            int col = i - PAD;
            double t = 0.0;
            #pragma unroll
            for (int r = 0; r < 8; ++r) t += part[(size_t)r * T_DIM + col];
            v = (float)(t * (1.0 / 1024.0));        // /1024 is exact
        }
        cm[i] = v;
    }
    if (i < C_CH * 16) {                       // tail columns NSTEPS..T_DIM-1
        int c = i >> 4, j = i & 15;
        size_t idx = (size_t)c * T_DIM + NSTEPS + j;
        out[idx] = inp[idx];
    }
}

// ---------------- scan helpers ----------------
// Swizzled LDS read: raw row byte offset b (16B-aligned) -> swizzled address.
// Segment sigma = b>>10 (1 KB per lane-segment); 16B chunk index within the
// segment is XORed with (sigma & 7) -> a wave's 64 lanes (uniform chunk,
// lane-varying sigma) spread over 8 bank groups: 2-way aliasing = free (m136).
__device__ __forceinline__ float4 swz_ld(const float* base, int b) {
    int a = (b & ~1023) | ((((b >> 4) & 63) ^ ((b >> 10) & 7)) << 4);
    return *(const float4*)((const char*)base + a);
}

// ---------------- Kernel 3: row-parallel per-channel scan ----------------
// One block = one channel. Lane l owns time segment [256*l, 256*l+256).
// Entire 64 KB row staged ONCE via 64 coalesced 1 KB global_load_lds ops
// (contiguous stream; swizzle applied on the global source address per
// G21/m173, matching XOR on the ds_read side). Lane l's 256-step warmup
// region == lane l-1's segment -> already in LDS, zero extra HBM fetch.
// No in-loop staging: single vmcnt(0) after prologue. cm read from global
// (65 KB, L2-resident). Spikes -> bitmask regs -> LDS -> coalesced stores.
__global__ __launch_bounds__(64) void scan_kernel(const float* __restrict__ inp,
                                                  const float* __restrict__ cm,
                                                  float* __restrict__ out) {
    __shared__ float    rowl[T_DIM + 8];   // 64 KB row (swizzled) + 32 B zero pad
    __shared__ uint32_t bm[64][8];         // 2 KB spike bitmasks

    const int ch   = blockIdx.x;
    const int lane = threadIdx.x;
    const float* row  = inp + (size_t)ch * T_DIM;
    float*       orow = out + (size_t)ch * T_DIM;

    // ---- prologue: stage full row, swizzled source, linear LDS dest ----
    #pragma unroll
    for (int i = 0; i < 64; ++i) {
        const float* src = row + i * SEG + ((lane ^ (i & 7)) << 2);
        __builtin_amdgcn_global_load_lds(
            (const __attribute__((address_space(1))) void*)src,
            (__attribute__((address_space(3))) void*)(rowl + i * SEG),
            16, 0, 0);
    }
    if (lane < 2) {   // zero pad: raw [16384, 16392) (right zero-pad of inp_padded)
        *(float4*)(rowl + T_DIM + lane * 4) = make_float4(0.f, 0.f, 0.f, 0.f);
    }
    asm volatile("s_waitcnt vmcnt(0)" ::: "memory");
    __builtin_amdgcn_sched_barrier(0);

    // ---- init window at padded position sW (warmup start; main start for lane 0) ----
    const int sW = (lane == 0) ? 0 : (lane - 1) * SEG;
    const int sM = lane * SEG;

    float xs[16], ms[16];
    {
        const float4* cp = (const float4*)(cm + sW);
        float4 m0 = cp[0], m1 = cp[1], m2 = cp[2], m3 = cp[3];
        float mt[16] = {m0.x,m0.y,m0.z,m0.w, m1.x,m1.y,m1.z,m1.w,
                        m2.x,m2.y,m2.z,m2.w, m3.x,m3.y,m3.z,m3.w};
        #pragma unroll
        for (int j = 0; j < 16; ++j) ms[j] = mt[j];

        if (sW == 0) {                        // lanes 0,1: padded [0,16) = 8 zeros + raw[0,8)
            float4 x2 = swz_ld(rowl, 0);
            float4 x3 = swz_ld(rowl, 16);
            float xt[8] = {x2.x,x2.y,x2.z,x2.w, x3.x,x3.y,x3.z,x3.w};
            #pragma unroll
            for (int j = 0; j < 8; ++j) { xs[j] = 0.0f; xs[j + 8] = xt[j]; }
        } else {                              // raw [sW-8, sW+8)
            const int b = sW * 4 - 32;
            float4 x0 = swz_ld(rowl, b),      x1 = swz_ld(rowl, b + 16),
                   x2 = swz_ld(rowl, b + 32), x3 = swz_ld(rowl, b + 48);
            float xt[16] = {x0.x,x0.y,x0.z,x0.w, x1.x,x1.y,x1.z,x1.w,
                            x2.x,x2.y,x2.z,x2.w, x3.x,x3.y,x3.z,x3.w};
            #pragma unroll
            for (int j = 0; j < 16; ++j) xs[j] = xt[j];
        }
    }
    float win = 0.0f;
    #pragma unroll
    for (int j = 0; j < 16; ++j) win = fmaf(xs[j], ms[j], win);

    float w = 1.0f, mem = 0.0f, spf = 0.0f;   // exact for lane 0 (t=0); warmup-converged otherwise

    // ---- warmup: 16 iterations, lanes 1..63 only (lane 0 exec-masked) ----
    for (int it = 0; it < 16; ++it) {
        if (lane != 0) {
            const int b = sW * 4 + it * 64 + 32;          // raw bytes of padded [t+16, t+32)
            float4 a0 = swz_ld(rowl, b),      a1 = swz_ld(rowl, b + 16),
                   a2 = swz_ld(rowl, b + 32), a3 = swz_ld(rowl, b + 48);
            const float4* cp = (const float4*)(cm + sW + it * 16 + 16);
            float4 b0 = cp[0], b1 = cp[1], b2 = cp[2], b3 = cp[3];
            float xn[16] = {a0.x,a0.y,a0.z,a0.w, a1.x,a1.y,a1.z,a1.w,
                            a2.x,a2.y,a2.z,a2.w, a3.x,a3.y,a3.z,a3.w};
            float mn[16] = {b0.x,b0.y,b0.z,b0.w, b1.x,b1.y,b1.z,b1.w,
                            b2.x,b2.y,b2.z,b2.w, b3.x,b3.y,b3.z,b3.w};
            #pragma unroll
            for (int j = 0; j < 16; ++j) {
                w = fminf(fmaxf(fmaf(0.5f, w, 0.5f * win), -1.0f), 3.0f);
                float x = xs[j];
                mem = fmaf(0.95f, mem, fmaf(w, x, -spf));   // spf = prev spike = reset
                spf = (mem > 1.0f) ? 1.0f : 0.0f;
                win = fmaf(xn[j], mn[j], fmaf(-x, ms[j], win));
                xs[j] = xn[j]; ms[j] = mn[j];
            }
        }
    }

    // ---- main: 16 unrolled iterations, all lanes; spikes -> bitmask regs ----
    uint32_t sb[8] = {0, 0, 0, 0, 0, 0, 0, 0};
    #pragma unroll
    for (int q = 0; q < 16; ++q) {
        const int b = sM * 4 + q * 64 + 32;
        float4 a0 = swz_ld(rowl, b),      a1 = swz_ld(rowl, b + 16),
               a2 = swz_ld(rowl, b + 32), a3 = swz_ld(rowl, b + 48);
        const float4* cp = (const float4*)(cm + sM + q * 16 + 16);
        float4 b0 = cp[0], b1 = cp[1], b2 = cp[2], b3 = cp[3];
        float xn[16] = {a0.x,a0.y,a0.z,a0.w, a1.x,a1.y,a1.z,a1.w,
                        a2.x,a2.y,a2.z,a2.w, a3.x,a3.y,a3.z,a3.w};
        float mn[16] = {b0.x,b0.y,b0.z,b0.w, b1.x,b1.y,b1.z,b1.w,
                        b2.x,b2.y,b2.z,b2.w, b3.x,b3.y,b3.z,b3.w};
        uint32_t m16 = 0;
        #pragma unroll
        for (int j = 0; j < 16; ++j) {
            w = fminf(fmaxf(fmaf(0.5f, w, 0.5f * win), -1.0f), 3.0f);
            float x = xs[j];
            mem = fmaf(0.95f, mem, fmaf(w, x, -spf));       // spf = prev spike = reset
            bool sp = (mem > 1.0f);
            spf = sp ? 1.0f : 0.0f;
            m16 |= sp ? (1u << j) : 0u;
            win = fmaf(xn[j], mn[j], fmaf(-x, ms[j], win));
            xs[j] = xn[j]; ms[j] = mn[j];
        }
        sb[q >> 1] |= m16 << ((q & 1) * 16);                // static index (q unrolled)
    }

    // ---- write: bitmask transpose via LDS -> 64 coalesced 1 KB row stores ----
    *(uint4*)&bm[lane][0] = make_uint4(sb[0], sb[1], sb[2], sb[3]);
    *(uint4*)&bm[lane][4] = make_uint4(sb[4], sb[5], sb[6], sb[7]);
    // single-wave RAW on LDS: compiler inserts lgkmcnt ordering
    #pragma unroll 8
    for (int seg = 0; seg < 64; ++seg) {
        uint32_t word = bm[seg][lane >> 3];                 // step s = lane*4+e; word s>>5
        uint32_t bits = (word >> ((lane & 7) * 4)) & 0xFu;  // bit s&31
        float4 v = make_float4((bits & 1u) ? 1.f : 0.f, (bits & 2u) ? 1.f : 0.f,
                               (bits & 4u) ? 1.f : 0.f, (bits & 8u) ? 1.f : 0.f);
        if (seg < 63 || lane < 60)   // positions >= NSTEPS are input-copy (colmean_tail)
            *(float4*)(orow + seg * SEG + lane * 4) = v;
    }
}

extern "C" void kernel_launch(void* const* d_in, const int* in_sizes, int n_in,
                              void* d_out, int out_size, void* d_ws, size_t ws_size,
                              hipStream_t stream) {
    const float* inp = (const float*)d_in[0];
    float* out = (float*)d_out;
    double* part = (double*)d_ws;
    float* cm = (float*)((char*)d_ws + WS_CM_OFFSET);

    colsum_partial<<<dim3(32, 8), 128, 0, stream>>>(inp, part);
    colmean_tail<<<dim3(65), 256, 0, stream>>>(part, inp, cm, out);
    scan_kernel<<<dim3(C_CH), 64, 0, stream>>>(inp, cm, out);
}